// Round 4
// baseline (324.704 us; speedup 1.0000x reference)
//
#include <hip/hip_runtime.h>
#include <hip/hip_bf16.h>
#include <stdint.h>

#define NB   16
#define CIN  256
#define CRED 64
#define HW   2304
#define JT_ATT  128  // j-tile per attn block (32 per wave)
#define NJT_ATT 18   // 2304/128
#define NIG  4       // i-dimension split groups (attn)
#define NIT  9       // 64-wide i-tiles per group (36/4)

typedef __bf16 bf16;
typedef __bf16 bf16x8 __attribute__((ext_vector_type(8)));
typedef __bf16 bf16x4 __attribute__((ext_vector_type(4)));
typedef float  f32x4  __attribute__((ext_vector_type(4)));

// ---------------- Kernel 0: weight prep (fp32 -> bf16; Wq,bq scaled by 1/ln2) ------
__global__ __launch_bounds__(256) void prep_kernel(
    const float* __restrict__ Wq, const float* __restrict__ bq,
    const float* __restrict__ Wk, const float* __restrict__ Wv,
    const float* __restrict__ Watt,
    bf16* __restrict__ Wqb, bf16* __restrict__ Wkb, bf16* __restrict__ Wvb,
    bf16* __restrict__ Wab, float* __restrict__ bqs)
{
    const float INVLN2 = 1.44269504088896f;
    int i = blockIdx.x * 256 + threadIdx.x;   // 64 blocks -> 16384 threads
    Wqb[i] = (bf16)(Wq[i] * INVLN2);
    Wkb[i] = (bf16)Wk[i];
    Wvb[i] = (bf16)Wv[i];
    Wab[i] = (bf16)Watt[i];
    if (i < CRED) bqs[i] = bq[i] * INVLN2;
}

// ---------------- Kernel 1: fused QKV 1x1 convs, 32-pos j-tiles, bf16 weights ------
// x [N][256][2304] f32 -> qT [N][2304][64] bf16 (q/ln2), kT [N][2304][64], v [N][64][2304]
__global__ __launch_bounds__(256) void qkv_kernel(
    const float* __restrict__ x,
    const bf16* __restrict__ Wqb, const float* __restrict__ bqs,
    const bf16* __restrict__ Wkb, const float* __restrict__ bk,
    const bf16* __restrict__ Wvb, const float* __restrict__ bv,
    bf16* __restrict__ qT, bf16* __restrict__ kT, bf16* __restrict__ v)
{
    __shared__ __align__(16) bf16 sX[32 * 264];  // xT[pos][cin], stride 264 (pad 8)
    const int jt = blockIdx.x, n = blockIdx.y;
    const int jbase = jt * 32;
    const int tid = threadIdx.x;
    const int lane = tid & 63, w = tid >> 6;
    const int l15 = lane & 15, q4 = lane >> 4;

    // stage xT (transpose + cvt bf16): coalesced float4 reads, scalar LDS writes
    const float* xn = x + ((size_t)n * CIN) * HW + jbase;
    #pragma unroll
    for (int it = 0; it < 8; ++it) {
        int idx = tid + 256 * it;          // 2048 float4s total
        int c = idx >> 3, p4 = idx & 7;
        const float4 vv = *(const float4*)(xn + c * HW + p4 * 4);
        sX[(p4 * 4 + 0) * 264 + c] = (bf16)vv.x;
        sX[(p4 * 4 + 1) * 264 + c] = (bf16)vv.y;
        sX[(p4 * 4 + 2) * 264 + c] = (bf16)vv.z;
        sX[(p4 * 4 + 3) * 264 + c] = (bf16)vv.w;
    }
    __syncthreads();

    const bf16*  Ws[3] = {Wqb, Wkb, Wvb};
    const float* bs[3] = {bqs, bk, bv};
    #pragma unroll
    for (int wi = 0; wi < 3; ++wi) {
        bf16x8 a[8];
        const bf16* Wp = Ws[wi] + (w * 16 + l15) * CIN + q4 * 8;
        #pragma unroll
        for (int ks = 0; ks < 8; ++ks) a[ks] = *(const bf16x8*)(Wp + ks * 32);
        f32x4 acc[2] = {};
        #pragma unroll
        for (int nt = 0; nt < 2; ++nt) {
            #pragma unroll
            for (int ks = 0; ks < 8; ++ks) {
                bf16x8 b = *(const bf16x8*)(sX + (nt * 16 + l15) * 264 + ks * 32 + q4 * 8);
                acc[nt] = __builtin_amdgcn_mfma_f32_16x16x32_bf16(a[ks], b, acc[nt], 0, 0, 0);
            }
        }
        const int crb = w * 16 + q4 * 4;   // C/D row = outc
        const float b0 = bs[wi][crb], b1 = bs[wi][crb + 1],
                    b2 = bs[wi][crb + 2], b3 = bs[wi][crb + 3];
        if (wi < 2) {
            bf16* dst = (wi == 0 ? qT : kT) + ((size_t)n * HW) * 64;
            #pragma unroll
            for (int nt = 0; nt < 2; ++nt) {
                int pos = jbase + nt * 16 + l15;
                bf16x4 pk = {(bf16)(acc[nt].x + b0), (bf16)(acc[nt].y + b1),
                             (bf16)(acc[nt].z + b2), (bf16)(acc[nt].w + b3)};
                *(bf16x4*)(dst + pos * 64 + crb) = pk;
            }
        } else {
            bf16* dst = v + ((size_t)n * CRED) * HW;
            #pragma unroll
            for (int nt = 0; nt < 2; ++nt) {
                int pos = jbase + nt * 16 + l15;
                dst[(crb + 0) * HW + pos] = (bf16)(acc[nt].x + b0);
                dst[(crb + 1) * HW + pos] = (bf16)(acc[nt].y + b1);
                dst[(crb + 2) * HW + pos] = (bf16)(acc[nt].z + b2);
                dst[(crb + 3) * HW + pos] = (bf16)(acc[nt].w + b3);
            }
        }
    }
}

// ---------------- Kernel 2: KtQ -> exp2 -> V*P, NO LDS, NO BARRIERS ----------------
// All 4 waves of a block read IDENTICAL K/V fragments -> L1 (16KB/tile) dedups;
// LDS staging and both barriers deleted. Waves free-run across iterations.
// P stays in own-lane registers (B-frag slot (q4,e) <-> i=(2g+(e>>2))*16+q4*4+(e&3));
// V A-frag = two contiguous b64 global chunks matching that i-order.
// XCD swizzle: 1152 blocks = 8 XCDs x 144; each XCD's chunk covers 2 n's ->
// K+V working set 1.2 MB -> L2-resident per XCD.
__global__ __launch_bounds__(256, 3) void attn_kernel(
    const bf16* __restrict__ qT, const bf16* __restrict__ kT,
    const bf16* __restrict__ v,
    float* __restrict__ OTp, float* __restrict__ Z)
{
    const int phys = blockIdx.x;
    const int virt = (phys & 7) * 144 + (phys >> 3);
    const int jt = virt % NJT_ATT;
    const int ig = (virt / NJT_ATT) & 3;
    const int n  = virt / (NJT_ATT * NIG);
    const int tid = threadIdx.x;
    const int lane = tid & 63, w = tid >> 6;
    const int l15 = lane & 15, q4 = lane >> 4;
    const int jb = jt * JT_ATT + w * 32;   // this wave's j-strip base

    // Q fragments (loop-invariant, register-resident)
    bf16x8 qf[2][2];
    {
        const bf16* qn = qT + ((size_t)n * HW + jb) * 64;
        #pragma unroll
        for (int nt = 0; nt < 2; ++nt)
            #pragma unroll
            for (int ks = 0; ks < 2; ++ks)
                qf[nt][ks] = *(const bf16x8*)(qn + (nt * 16 + l15) * 64 + ks * 32 + q4 * 8);
    }

    f32x4 oacc[4][2] = {};   // [c-tile][j-subtile]
    float zacc = 0.f;
    const bf16* kb = kT + ((size_t)n * HW) * 64;
    const bf16* vb = v + ((size_t)n * CRED) * HW;
    const int ibase0 = ig * NIT * 64;

    for (int it = 0; it < NIT; ++it) {
        const int ibase = ibase0 + it * 64;

        // K fragments: 8 x b128 direct from kT (layout == A-frag layout)
        bf16x8 kf[4][2];
        #pragma unroll
        for (int is = 0; is < 4; ++is) {
            const bf16* kp = kb + (size_t)(ibase + is * 16 + l15) * 64 + q4 * 8;
            kf[is][0] = *(const bf16x8*)(kp);
            kf[is][1] = *(const bf16x8*)(kp + 32);
        }
        // V fragments for i-block g: element e -> V[row][(2g+(e>>2))*16+q4*4+(e&3)]
        // = two b64 chunks at col g*32+q4*4 and g*32+16+q4*4 (contiguous in v).
        bf16x8 vf0[4];
        #pragma unroll
        for (int ct = 0; ct < 4; ++ct) {
            const bf16* vp = vb + (size_t)(ct * 16 + l15) * HW + ibase + q4 * 4;
            union { uint32_t u[4]; bf16x8 v8; } t;
            uint2 a0 = *(const uint2*)(vp);
            uint2 a1 = *(const uint2*)(vp + 16);
            t.u[0] = a0.x; t.u[1] = a0.y; t.u[2] = a1.x; t.u[3] = a1.y;
            vf0[ct] = t.v8;
        }

        unsigned pw[2][4][2];
        // QK for is = 0,1
        #pragma unroll
        for (int is = 0; is < 2; ++is) {
            #pragma unroll
            for (int nt = 0; nt < 2; ++nt) {
                f32x4 s = {};
                s = __builtin_amdgcn_mfma_f32_16x16x32_bf16(kf[is][0], qf[nt][0], s, 0, 0, 0);
                s = __builtin_amdgcn_mfma_f32_16x16x32_bf16(kf[is][1], qf[nt][1], s, 0, 0, 0);
                float p0, p1, p2, p3;
                asm("v_exp_f32 %0, %1" : "=v"(p0) : "v"(s.x));
                asm("v_exp_f32 %0, %1" : "=v"(p1) : "v"(s.y));
                asm("v_exp_f32 %0, %1" : "=v"(p2) : "v"(s.z));
                asm("v_exp_f32 %0, %1" : "=v"(p3) : "v"(s.w));
                zacc += (p0 + p1) + (p2 + p3);
                asm("v_cvt_pk_bf16_f32 %0, %1, %2" : "=v"(pw[nt][is][0]) : "v"(p0), "v"(p1));
                asm("v_cvt_pk_bf16_f32 %0, %1, %2" : "=v"(pw[nt][is][1]) : "v"(p2), "v"(p3));
            }
        }
        // V fragments for g=1 (issued while PV g=0 runs)
        bf16x8 vf1[4];
        #pragma unroll
        for (int ct = 0; ct < 4; ++ct) {
            const bf16* vp = vb + (size_t)(ct * 16 + l15) * HW + ibase + 32 + q4 * 4;
            union { uint32_t u[4]; bf16x8 v8; } t;
            uint2 a0 = *(const uint2*)(vp);
            uint2 a1 = *(const uint2*)(vp + 16);
            t.u[0] = a0.x; t.u[1] = a0.y; t.u[2] = a1.x; t.u[3] = a1.y;
            vf1[ct] = t.v8;
        }
        // PV for g=0 (is 0,1)
        #pragma unroll
        for (int nt = 0; nt < 2; ++nt) {
            union { unsigned u[4]; bf16x8 v8; } pb;
            pb.u[0] = pw[nt][0][0]; pb.u[1] = pw[nt][0][1];
            pb.u[2] = pw[nt][1][0]; pb.u[3] = pw[nt][1][1];
            #pragma unroll
            for (int ct = 0; ct < 4; ++ct)
                oacc[ct][nt] = __builtin_amdgcn_mfma_f32_16x16x32_bf16(
                    vf0[ct], pb.v8, oacc[ct][nt], 0, 0, 0);
        }
        // QK for is = 2,3
        #pragma unroll
        for (int is = 2; is < 4; ++is) {
            #pragma unroll
            for (int nt = 0; nt < 2; ++nt) {
                f32x4 s = {};
                s = __builtin_amdgcn_mfma_f32_16x16x32_bf16(kf[is][0], qf[nt][0], s, 0, 0, 0);
                s = __builtin_amdgcn_mfma_f32_16x16x32_bf16(kf[is][1], qf[nt][1], s, 0, 0, 0);
                float p0, p1, p2, p3;
                asm("v_exp_f32 %0, %1" : "=v"(p0) : "v"(s.x));
                asm("v_exp_f32 %0, %1" : "=v"(p1) : "v"(s.y));
                asm("v_exp_f32 %0, %1" : "=v"(p2) : "v"(s.z));
                asm("v_exp_f32 %0, %1" : "=v"(p3) : "v"(s.w));
                zacc += (p0 + p1) + (p2 + p3);
                asm("v_cvt_pk_bf16_f32 %0, %1, %2" : "=v"(pw[nt][is][0]) : "v"(p0), "v"(p1));
                asm("v_cvt_pk_bf16_f32 %0, %1, %2" : "=v"(pw[nt][is][1]) : "v"(p2), "v"(p3));
            }
        }
        // PV for g=1 (is 2,3)
        #pragma unroll
        for (int nt = 0; nt < 2; ++nt) {
            union { unsigned u[4]; bf16x8 v8; } pb;
            pb.u[0] = pw[nt][2][0]; pb.u[1] = pw[nt][2][1];
            pb.u[2] = pw[nt][3][0]; pb.u[3] = pw[nt][3][1];
            #pragma unroll
            for (int ct = 0; ct < 4; ++ct)
                oacc[ct][nt] = __builtin_amdgcn_mfma_f32_16x16x32_bf16(
                    vf1[ct], pb.v8, oacc[ct][nt], 0, 0, 0);
        }
    }
    // write unnormalized partial O transposed: OTp[ig][n][pos][cr]
    float* OTn = OTp + (((size_t)ig * NB + n) * HW) * 64;
    #pragma unroll
    for (int ct = 0; ct < 4; ++ct)
        #pragma unroll
        for (int nt = 0; nt < 2; ++nt) {
            int pos = jb + nt * 16 + l15;
            *(f32x4*)(OTn + (size_t)pos * 64 + ct * 16 + q4 * 4) = oacc[ct][nt];
        }
    // per-batch Z: wave reduce then one atomic per wave
    #pragma unroll
    for (int off = 32; off > 0; off >>= 1) zacc += __shfl_down(zacc, off);
    if (lane == 0) atomicAdd(Z + n, zacc);
}

// ---------------- Kernel 3: out = g * (Watt @ (sum(O)/Z) + batt) + g ---------------
// 32-pos j-tiles: grid (72, 16) = 1152 blocks for latency hiding
__global__ __launch_bounds__(256) void out_kernel(
    const float* __restrict__ OTp, const float* __restrict__ Z,
    const bf16* __restrict__ Wab, const float* __restrict__ batt,
    const float* __restrict__ g, float* __restrict__ out)
{
    __shared__ __align__(16) bf16 sO[32 * 72];  // normalized O, [pos][cr]
    const int jt = blockIdx.x, n = blockIdx.y;
    const int jbase = jt * 32;
    const int tid = threadIdx.x;
    const int lane = tid & 63, w = tid >> 6;
    const int l15 = lane & 15, q4 = lane >> 4;
    const float invZ = 1.0f / Z[n];

    // sum NIG partials, normalize, cvt bf16
    #pragma unroll
    for (int i0 = 0; i0 < 2; ++i0) {
        int i = tid + i0 * 256;
        int r = i >> 4, c4 = i & 15;
        const float* p = OTp + (((size_t)n * HW) + jbase + r) * 64 + c4 * 4;
        float4 s = *(const float4*)(p);
        #pragma unroll
        for (int igx = 1; igx < NIG; ++igx) {
            float4 t = *(const float4*)(p + (size_t)igx * NB * HW * 64);
            s.x += t.x; s.y += t.y; s.z += t.z; s.w += t.w;
        }
        bf16x4 pk = {(bf16)(s.x * invZ), (bf16)(s.y * invZ),
                     (bf16)(s.z * invZ), (bf16)(s.w * invZ)};
        *(bf16x4*)(sO + r * 72 + c4 * 4) = pk;
    }
    __syncthreads();

    bf16x8 bfr[2][2];
    #pragma unroll
    for (int nt = 0; nt < 2; ++nt)
        #pragma unroll
        for (int ks = 0; ks < 2; ++ks)
            bfr[nt][ks] = *(const bf16x8*)(sO + (nt * 16 + l15) * 72 + ks * 32 + q4 * 8);

    const float* gp = g + ((size_t)n * CIN) * HW;
    float* op = out + ((size_t)n * CIN) * HW;
    #pragma unroll
    for (int mt = 0; mt < 4; ++mt) {
        const bf16* Wp = Wab + (w * 64 + mt * 16 + l15) * 64 + q4 * 8;
        bf16x8 a0 = *(const bf16x8*)(Wp);
        bf16x8 a1 = *(const bf16x8*)(Wp + 32);
        const int co = w * 64 + mt * 16 + q4 * 4;
        const float c0 = batt[co], c1 = batt[co + 1], c2 = batt[co + 2], c3 = batt[co + 3];
        #pragma unroll
        for (int nt = 0; nt < 2; ++nt) {
            f32x4 acc = {};
            acc = __builtin_amdgcn_mfma_f32_16x16x32_bf16(a0, bfr[nt][0], acc, 0, 0, 0);
            acc = __builtin_amdgcn_mfma_f32_16x16x32_bf16(a1, bfr[nt][1], acc, 0, 0, 0);
            const int pos = jbase + nt * 16 + l15;
            const float g0 = gp[(co + 0) * HW + pos], g1 = gp[(co + 1) * HW + pos];
            const float g2 = gp[(co + 2) * HW + pos], g3 = gp[(co + 3) * HW + pos];
            op[(co + 0) * HW + pos] = g0 * (acc.x + c0 + 1.0f);
            op[(co + 1) * HW + pos] = g1 * (acc.y + c1 + 1.0f);
            op[(co + 2) * HW + pos] = g2 * (acc.z + c2 + 1.0f);
            op[(co + 3) * HW + pos] = g3 * (acc.w + c3 + 1.0f);
        }
    }
}

extern "C" void kernel_launch(void* const* d_in, const int* in_sizes, int n_in,
                              void* d_out, int out_size, void* d_ws, size_t ws_size,
                              hipStream_t stream) {
    const float* x    = (const float*)d_in[0];
    const float* g    = (const float*)d_in[1];
    const float* Wq   = (const float*)d_in[2];
    const float* bq   = (const float*)d_in[3];
    const float* Wk   = (const float*)d_in[4];
    const float* bk   = (const float*)d_in[5];
    const float* Wv   = (const float*)d_in[6];
    const float* bv   = (const float*)d_in[7];
    const float* Watt = (const float*)d_in[8];
    const float* batt = (const float*)d_in[9];
    float* out = (float*)d_out;

    char* ws = (char*)d_ws;
    const size_t qkv_sz = (size_t)NB * HW * CRED * sizeof(bf16);   // 4,718,592 B
    bf16*  qT  = (bf16*)(ws);
    bf16*  kT  = (bf16*)(ws + qkv_sz);
    bf16*  vv  = (bf16*)(ws + 2 * qkv_sz);
    float* OTp = (float*)(ws + 3 * qkv_sz);                        // NIG x 9,437,184 B
    char*  w2  = ws + 3 * qkv_sz + (size_t)NIG * NB * HW * CRED * sizeof(float);
    float* Zp  = (float*)(w2);
    bf16*  Wqb = (bf16*)(w2 + 256);
    bf16*  Wkb = Wqb + CRED * CIN;
    bf16*  Wvb = Wkb + CRED * CIN;
    bf16*  Wab = Wvb + CRED * CIN;
    float* bqs = (float*)(Wab + CIN * CRED);

    hipMemsetAsync(Zp, 0, NB * sizeof(float), stream);

    dim3 blk(256);
    prep_kernel<<<dim3(64), blk, 0, stream>>>(Wq, bq, Wk, Wv, Watt, Wqb, Wkb, Wvb, Wab, bqs);
    qkv_kernel<<<dim3(HW / 32, NB), blk, 0, stream>>>(x, Wqb, bqs, Wkb, bk, Wvb, bv, qT, kT, vv);
    attn_kernel<<<dim3(NJT_ATT * NIG * NB), blk, 0, stream>>>(qT, kT, vv, OTp, Zp);
    out_kernel<<<dim3(HW / 32, NB), blk, 0, stream>>>(OTp, Zp, Wab, batt, g, out);
}

// Round 5
// 225.452 us; speedup vs baseline: 1.4402x; 1.4402x over previous
//
#include <hip/hip_runtime.h>
#include <hip/hip_bf16.h>
#include <stdint.h>

#define NB   16
#define CIN  256
#define CRED 64
#define HW   2304
#define JT_ATT  128  // j-tile per attn block (32 per wave)
#define NJT_ATT 18   // 2304/128
#define NIG  2       // i-dimension split groups (attn)
#define NIT  18      // 64-wide i-tiles per group (36/2)

typedef __bf16 bf16;
typedef __bf16 bf16x8 __attribute__((ext_vector_type(8)));
typedef __bf16 bf16x4 __attribute__((ext_vector_type(4)));
typedef __bf16 bf16x2 __attribute__((ext_vector_type(2)));
typedef float  f32x4  __attribute__((ext_vector_type(4)));

// ---------------- Kernel 0: weight prep (fp32 -> bf16; Wq,bq scaled by 1/ln2) ------
__global__ __launch_bounds__(256) void prep_kernel(
    const float* __restrict__ Wq, const float* __restrict__ bq,
    const float* __restrict__ Wk, const float* __restrict__ Wv,
    const float* __restrict__ Watt,
    bf16* __restrict__ Wqb, bf16* __restrict__ Wkb, bf16* __restrict__ Wvb,
    bf16* __restrict__ Wab, float* __restrict__ bqs)
{
    const float INVLN2 = 1.44269504088896f;
    int i = blockIdx.x * 256 + threadIdx.x;   // 64 blocks -> 16384 threads
    Wqb[i] = (bf16)(Wq[i] * INVLN2);
    Wkb[i] = (bf16)Wk[i];
    Wvb[i] = (bf16)Wv[i];
    Wab[i] = (bf16)Watt[i];
    if (i < CRED) bqs[i] = bq[i] * INVLN2;
}

// ---------------- Kernel 1: fused QKV 1x1 convs, 32-pos j-tiles, bf16 weights ------
// x [N][256][2304] f32 -> qT [N][2304][64] bf16 (q/ln2), kT [N][2304][64], v [N][64][2304]
// Staging writes paired channels as b32; V output bounced via LDS for coalesced store.
__global__ __launch_bounds__(256) void qkv_kernel(
    const float* __restrict__ x,
    const bf16* __restrict__ Wqb, const float* __restrict__ bqs,
    const bf16* __restrict__ Wkb, const float* __restrict__ bk,
    const bf16* __restrict__ Wvb, const float* __restrict__ bv,
    bf16* __restrict__ qT, bf16* __restrict__ kT, bf16* __restrict__ v)
{
    __shared__ __align__(16) bf16 sX[32 * 264];  // xT[pos][cin], stride 264 (pad 8)
    __shared__ __align__(16) bf16 sVt[64 * 40];  // v bounce [cr][pos], stride 40
    const int jt = blockIdx.x, n = blockIdx.y;
    const int jbase = jt * 32;
    const int tid = threadIdx.x;
    const int lane = tid & 63, w = tid >> 6;
    const int l15 = lane & 15, q4 = lane >> 4;

    // stage xT: paired channels -> bf16x2 b32 LDS writes (conflict-free pattern)
    const float* xn = x + ((size_t)n * CIN) * HW + jbase;
    #pragma unroll
    for (int it = 0; it < 4; ++it) {
        int idx = tid + 256 * it;          // 1024 items: cp 0..127, p4 0..7
        int cp = idx >> 3, p4 = idx & 7;
        const int c = cp * 2;
        const float4 va = *(const float4*)(xn + (size_t)c * HW + p4 * 4);
        const float4 vb = *(const float4*)(xn + (size_t)(c + 1) * HW + p4 * 4);
        bf16x2 e0 = {(bf16)va.x, (bf16)vb.x};
        bf16x2 e1 = {(bf16)va.y, (bf16)vb.y};
        bf16x2 e2 = {(bf16)va.z, (bf16)vb.z};
        bf16x2 e3 = {(bf16)va.w, (bf16)vb.w};
        bf16* sp = sX + c;
        *(bf16x2*)(sp + (p4 * 4 + 0) * 264) = e0;
        *(bf16x2*)(sp + (p4 * 4 + 1) * 264) = e1;
        *(bf16x2*)(sp + (p4 * 4 + 2) * 264) = e2;
        *(bf16x2*)(sp + (p4 * 4 + 3) * 264) = e3;
    }
    __syncthreads();

    const bf16*  Ws[3] = {Wqb, Wkb, Wvb};
    const float* bs[3] = {bqs, bk, bv};
    #pragma unroll
    for (int wi = 0; wi < 3; ++wi) {
        bf16x8 a[8];
        const bf16* Wp = Ws[wi] + (w * 16 + l15) * CIN + q4 * 8;
        #pragma unroll
        for (int ks = 0; ks < 8; ++ks) a[ks] = *(const bf16x8*)(Wp + ks * 32);
        f32x4 acc[2] = {};
        #pragma unroll
        for (int nt = 0; nt < 2; ++nt) {
            #pragma unroll
            for (int ks = 0; ks < 8; ++ks) {
                bf16x8 b = *(const bf16x8*)(sX + (nt * 16 + l15) * 264 + ks * 32 + q4 * 8);
                acc[nt] = __builtin_amdgcn_mfma_f32_16x16x32_bf16(a[ks], b, acc[nt], 0, 0, 0);
            }
        }
        const int crb = w * 16 + q4 * 4;   // C/D row = outc
        const float b0 = bs[wi][crb], b1 = bs[wi][crb + 1],
                    b2 = bs[wi][crb + 2], b3 = bs[wi][crb + 3];
        if (wi < 2) {
            bf16* dst = (wi == 0 ? qT : kT) + ((size_t)n * HW) * 64;
            #pragma unroll
            for (int nt = 0; nt < 2; ++nt) {
                int pos = jbase + nt * 16 + l15;
                bf16x4 pk = {(bf16)(acc[nt].x + b0), (bf16)(acc[nt].y + b1),
                             (bf16)(acc[nt].z + b2), (bf16)(acc[nt].w + b3)};
                *(bf16x4*)(dst + pos * 64 + crb) = pk;
            }
        } else {
            // bounce V through LDS for coalesced global stores
            #pragma unroll
            for (int nt = 0; nt < 2; ++nt) {
                int pl = nt * 16 + l15;
                sVt[(crb + 0) * 40 + pl] = (bf16)(acc[nt].x + b0);
                sVt[(crb + 1) * 40 + pl] = (bf16)(acc[nt].y + b1);
                sVt[(crb + 2) * 40 + pl] = (bf16)(acc[nt].z + b2);
                sVt[(crb + 3) * 40 + pl] = (bf16)(acc[nt].w + b3);
            }
        }
    }
    __syncthreads();
    // coalesced V store: thread -> 8 consecutive pos of one cr row (16B)
    {
        const int cr = tid >> 2, p8 = (tid & 3) * 8;
        uint4 val = *(const uint4*)(sVt + cr * 40 + p8);
        *(uint4*)(v + ((size_t)n * CRED + cr) * HW + jbase + p8) = val;
    }
}

// ---------------- Kernel 2: fused KtQ -> exp -> V*P, no cross-lane, 1 barrier/iter --
// Wave w owns j-strip [w*32, w*32+32). P stays in registers (own-lane B-frag assembly;
// V columns staged permuted p(i) = (i&0x23)|((i&0xC)<<1)|((i>>2)&4)). Double-buffered
// sK/sV -> single barrier/iter: compute(buf) -> stage(buf^1) -> issue loads(t+2) -> bar.
// Grid 576 = 8 XCD x 72 chunk-swizzled: each XCD touches K/V of exactly 2 n's (L2-fit).
__global__ __launch_bounds__(256, 4) void attn_kernel(
    const bf16* __restrict__ qT, const bf16* __restrict__ kT,
    const bf16* __restrict__ v,
    float* __restrict__ OTp, float* __restrict__ Z)
{
    __shared__ __align__(16) bf16 sK[2][64 * 72];
    __shared__ __align__(16) bf16 sV[2][64 * 72];   // column-permuted V tiles
    const int phys = blockIdx.x;
    const int virt = (phys & 7) * 72 + (phys >> 3);
    const int n  = virt / (NJT_ATT * NIG);
    const int r_ = virt % (NJT_ATT * NIG);
    const int jt = r_ % NJT_ATT;
    const int ig = r_ / NJT_ATT;
    const int jbase = jt * JT_ATT;
    const int tid = threadIdx.x;
    const int lane = tid & 63, w = tid >> 6;
    const int l15 = lane & 15, q4 = lane >> 4;

    // Q fragments direct from global (L2-resident, loop-invariant)
    bf16x8 qf[2][2];
    {
        const bf16* qn = qT + ((size_t)n * HW + jbase + w * 32) * 64;
        #pragma unroll
        for (int nt = 0; nt < 2; ++nt)
            #pragma unroll
            for (int ks = 0; ks < 2; ++ks)
                qf[nt][ks] = *(const bf16x8*)(qn + (nt * 16 + l15) * 64 + ks * 32 + q4 * 8);
    }

    f32x4 oacc[4][2] = {};   // [c-tile][j-subtile]
    float zacc = 0.f;
    const uint4* ksrc = (const uint4*)(kT + ((size_t)n * HW) * 64);
    const bf16* vbase = v + ((size_t)n * CRED) * HW;

    const int r0 = tid >> 3, c0 = tid & 7;
    const int ibase0 = ig * NIT * 64;
    // V staging permutation: thread's 8 i-cols (c0*8..+7) land as two uint2 groups
    const int pbase = ((c0 >> 2) & 1) * 32 + (c0 & 1) * 16 + ((c0 >> 1) & 1) * 4;

    // prologue: load tile 0 into regs
    uint4 kr0 = ksrc[(ibase0 + r0) * 8 + c0];
    uint4 kr1 = ksrc[(ibase0 + r0 + 32) * 8 + c0];
    uint4 vr0 = *(const uint4*)(vbase + (size_t)r0 * HW + ibase0 + c0 * 8);
    uint4 vr1 = *(const uint4*)(vbase + (size_t)(r0 + 32) * HW + ibase0 + c0 * 8);

    auto stage = [&](int buf) {
        uint4* dk = (uint4*)sK[buf];
        dk[r0 * 9 + c0] = kr0;
        dk[(r0 + 32) * 9 + c0] = kr1;
        bf16* dv0 = sV[buf] + r0 * 72 + pbase;
        bf16* dv1 = sV[buf] + (r0 + 32) * 72 + pbase;
        uint2 t;
        t.x = vr0.x; t.y = vr0.y; *(uint2*)(dv0)     = t;
        t.x = vr0.z; t.y = vr0.w; *(uint2*)(dv0 + 8) = t;
        t.x = vr1.x; t.y = vr1.y; *(uint2*)(dv1)     = t;
        t.x = vr1.z; t.y = vr1.w; *(uint2*)(dv1 + 8) = t;
    };

    // stage tile 0 into buf0, then prefetch tile 1
    stage(0);
    {
        const int nb = ibase0 + 64;
        kr0 = ksrc[(nb + r0) * 8 + c0];
        kr1 = ksrc[(nb + r0 + 32) * 8 + c0];
        vr0 = *(const uint4*)(vbase + (size_t)r0 * HW + nb + c0 * 8);
        vr1 = *(const uint4*)(vbase + (size_t)(r0 + 32) * HW + nb + c0 * 8);
    }
    __syncthreads();

    for (int it = 0; it < NIT; ++it) {
        const int cur = it & 1;
        const bf16* K = sK[cur];
        const bf16* V = sV[cur];

        // S' = (K_i^T Q_j)/ln2 for all 64 i x this wave's 32 j; P packed to bf16 regs
        unsigned pw[2][4][2];
        #pragma unroll
        for (int is = 0; is < 4; ++is) {
            bf16x8 kf0 = *(const bf16x8*)(K + (is * 16 + l15) * 72 + q4 * 8);
            bf16x8 kf1 = *(const bf16x8*)(K + (is * 16 + l15) * 72 + 32 + q4 * 8);
            #pragma unroll
            for (int nt = 0; nt < 2; ++nt) {
                f32x4 s = {};
                s = __builtin_amdgcn_mfma_f32_16x16x32_bf16(kf0, qf[nt][0], s, 0, 0, 0);
                s = __builtin_amdgcn_mfma_f32_16x16x32_bf16(kf1, qf[nt][1], s, 0, 0, 0);
                float p0 = exp2f(s.x), p1 = exp2f(s.y);
                float p2 = exp2f(s.z), p3 = exp2f(s.w);
                zacc += (p0 + p1) + (p2 + p3);
                unsigned w0, w1;
                asm("v_cvt_pk_bf16_f32 %0, %1, %2" : "=v"(w0) : "v"(p0), "v"(p1));
                asm("v_cvt_pk_bf16_f32 %0, %1, %2" : "=v"(w1) : "v"(p2), "v"(p3));
                pw[nt][is][0] = w0;
                pw[nt][is][1] = w1;
            }
        }
        // O += V_i * P: B-frags assembled from OWN-lane registers (V cols permuted)
        #pragma unroll
        for (int g = 0; g < 2; ++g) {
            bf16x8 vf[4];
            #pragma unroll
            for (int ct = 0; ct < 4; ++ct)
                vf[ct] = *(const bf16x8*)(V + (ct * 16 + l15) * 72 + g * 32 + q4 * 8);
            __builtin_amdgcn_s_setprio(1);
            #pragma unroll
            for (int nt = 0; nt < 2; ++nt) {
                union { unsigned u[4]; bf16x8 v8; } pb;
                pb.u[0] = pw[nt][2 * g][0];
                pb.u[1] = pw[nt][2 * g][1];
                pb.u[2] = pw[nt][2 * g + 1][0];
                pb.u[3] = pw[nt][2 * g + 1][1];
                #pragma unroll
                for (int ct = 0; ct < 4; ++ct)
                    oacc[ct][nt] = __builtin_amdgcn_mfma_f32_16x16x32_bf16(
                        vf[ct], pb.v8, oacc[ct][nt], 0, 0, 0);
            }
            __builtin_amdgcn_s_setprio(0);
        }

        if (it + 1 < NIT) {
            // stage tile it+1 (in regs since last iter) into the other buffer
            stage(cur ^ 1);
            // issue loads for tile it+2 (dummy reload of tile 0 on the tail)
            const int nb = ibase0 + ((it + 2 < NIT) ? (it + 2) * 64 : 0);
            kr0 = ksrc[(nb + r0) * 8 + c0];
            kr1 = ksrc[(nb + r0 + 32) * 8 + c0];
            vr0 = *(const uint4*)(vbase + (size_t)r0 * HW + nb + c0 * 8);
            vr1 = *(const uint4*)(vbase + (size_t)(r0 + 32) * HW + nb + c0 * 8);
            __syncthreads();
        }
    }
    // write unnormalized partial O transposed: OTp[ig][n][pos][cr]
    float* OTn = OTp + (((size_t)ig * NB + n) * HW) * 64;
    #pragma unroll
    for (int ct = 0; ct < 4; ++ct)
        #pragma unroll
        for (int nt = 0; nt < 2; ++nt) {
            int pos = jbase + w * 32 + nt * 16 + l15;
            *(f32x4*)(OTn + (size_t)pos * 64 + ct * 16 + q4 * 4) = oacc[ct][nt];
        }
    // per-batch Z: wave reduce then one atomic per wave
    #pragma unroll
    for (int off = 32; off > 0; off >>= 1) zacc += __shfl_down(zacc, off);
    if (lane == 0) atomicAdd(Z + n, zacc);
}

// ---------------- Kernel 3: out = g * (Watt @ (sum(O)/Z) + batt) + g ---------------
// 32-pos j-tiles: grid (72, 16) = 1152 blocks for latency hiding
__global__ __launch_bounds__(256) void out_kernel(
    const float* __restrict__ OTp, const float* __restrict__ Z,
    const bf16* __restrict__ Wab, const float* __restrict__ batt,
    const float* __restrict__ g, float* __restrict__ out)
{
    __shared__ __align__(16) bf16 sO[32 * 72];  // normalized O, [pos][cr]
    const int jt = blockIdx.x, n = blockIdx.y;
    const int jbase = jt * 32;
    const int tid = threadIdx.x;
    const int lane = tid & 63, w = tid >> 6;
    const int l15 = lane & 15, q4 = lane >> 4;
    const float invZ = 1.0f / Z[n];

    // sum NIG partials, normalize, cvt bf16
    #pragma unroll
    for (int i0 = 0; i0 < 2; ++i0) {
        int i = tid + i0 * 256;
        int r = i >> 4, c4 = i & 15;
        const float* p = OTp + (((size_t)n * HW) + jbase + r) * 64 + c4 * 4;
        float4 s = *(const float4*)(p);
        #pragma unroll
        for (int igx = 1; igx < NIG; ++igx) {
            float4 t = *(const float4*)(p + (size_t)igx * NB * HW * 64);
            s.x += t.x; s.y += t.y; s.z += t.z; s.w += t.w;
        }
        bf16x4 pk = {(bf16)(s.x * invZ), (bf16)(s.y * invZ),
                     (bf16)(s.z * invZ), (bf16)(s.w * invZ)};
        *(bf16x4*)(sO + r * 72 + c4 * 4) = pk;
    }
    __syncthreads();

    bf16x8 bfr[2][2];
    #pragma unroll
    for (int nt = 0; nt < 2; ++nt)
        #pragma unroll
        for (int ks = 0; ks < 2; ++ks)
            bfr[nt][ks] = *(const bf16x8*)(sO + (nt * 16 + l15) * 72 + ks * 32 + q4 * 8);

    const float* gp = g + ((size_t)n * CIN) * HW;
    float* op = out + ((size_t)n * CIN) * HW;
    #pragma unroll
    for (int mt = 0; mt < 4; ++mt) {
        const bf16* Wp = Wab + (w * 64 + mt * 16 + l15) * 64 + q4 * 8;
        bf16x8 a0 = *(const bf16x8*)(Wp);
        bf16x8 a1 = *(const bf16x8*)(Wp + 32);
        const int co = w * 64 + mt * 16 + q4 * 4;
        const float c0 = batt[co], c1 = batt[co + 1], c2 = batt[co + 2], c3 = batt[co + 3];
        #pragma unroll
        for (int nt = 0; nt < 2; ++nt) {
            f32x4 acc = {};
            acc = __builtin_amdgcn_mfma_f32_16x16x32_bf16(a0, bfr[nt][0], acc, 0, 0, 0);
            acc = __builtin_amdgcn_mfma_f32_16x16x32_bf16(a1, bfr[nt][1], acc, 0, 0, 0);
            const int pos = jbase + nt * 16 + l15;
            const float g0 = gp[(co + 0) * HW + pos], g1 = gp[(co + 1) * HW + pos];
            const float g2 = gp[(co + 2) * HW + pos], g3 = gp[(co + 3) * HW + pos];
            op[(co + 0) * HW + pos] = g0 * (acc.x + c0 + 1.0f);
            op[(co + 1) * HW + pos] = g1 * (acc.y + c1 + 1.0f);
            op[(co + 2) * HW + pos] = g2 * (acc.z + c2 + 1.0f);
            op[(co + 3) * HW + pos] = g3 * (acc.w + c3 + 1.0f);
        }
    }
}

extern "C" void kernel_launch(void* const* d_in, const int* in_sizes, int n_in,
                              void* d_out, int out_size, void* d_ws, size_t ws_size,
                              hipStream_t stream) {
    const float* x    = (const float*)d_in[0];
    const float* g    = (const float*)d_in[1];
    const float* Wq   = (const float*)d_in[2];
    const float* bq   = (const float*)d_in[3];
    const float* Wk   = (const float*)d_in[4];
    const float* bk   = (const float*)d_in[5];
    const float* Wv   = (const float*)d_in[6];
    const float* bv   = (const float*)d_in[7];
    const float* Watt = (const float*)d_in[8];
    const float* batt = (const float*)d_in[9];
    float* out = (float*)d_out;

    char* ws = (char*)d_ws;
    const size_t qkv_sz = (size_t)NB * HW * CRED * sizeof(bf16);   // 4,718,592 B
    bf16*  qT  = (bf16*)(ws);
    bf16*  kT  = (bf16*)(ws + qkv_sz);
    bf16*  vv  = (bf16*)(ws + 2 * qkv_sz);
    float* OTp = (float*)(ws + 3 * qkv_sz);                        // NIG x 9,437,184 B
    char*  w2  = ws + 3 * qkv_sz + (size_t)NIG * NB * HW * CRED * sizeof(float);
    float* Zp  = (float*)(w2);
    bf16*  Wqb = (bf16*)(w2 + 256);
    bf16*  Wkb = Wqb + CRED * CIN;
    bf16*  Wvb = Wkb + CRED * CIN;
    bf16*  Wab = Wvb + CRED * CIN;
    float* bqs = (float*)(Wab + CIN * CRED);

    hipMemsetAsync(Zp, 0, NB * sizeof(float), stream);

    dim3 blk(256);
    prep_kernel<<<dim3(64), blk, 0, stream>>>(Wq, bq, Wk, Wv, Watt, Wqb, Wkb, Wvb, Wab, bqs);
    qkv_kernel<<<dim3(HW / 32, NB), blk, 0, stream>>>(x, Wqb, bqs, Wkb, bk, Wvb, bv, qT, kT, vv);
    attn_kernel<<<dim3(NJT_ATT * NIG * NB), blk, 0, stream>>>(qT, kT, vv, OTp, Zp);
    out_kernel<<<dim3(HW / 32, NB), blk, 0, stream>>>(OTp, Zp, Wab, batt, g, out);
}